// Round 5
// baseline (1378.607 us; speedup 1.0000x reference)
//
#include <hip/hip_runtime.h>
#include <cstdint>

#define IN_F 4096
#define OUT_F 4096
#define M_TOT 8192     // BATCH*SEQ = 4*2048
#define TOTAL_R 63

typedef __attribute__((ext_vector_type(8))) short bf16x8;
typedef __attribute__((ext_vector_type(4))) float f32x4;
typedef __attribute__((ext_vector_type(16))) float f32x16;
typedef __attribute__((ext_vector_type(8))) unsigned short u16x8;
typedef __attribute__((ext_vector_type(4))) unsigned short u16x4;

__device__ __forceinline__ uint16_t f2bf_rn(float f) {
  uint32_t u = __float_as_uint(f);
  u += 0x7fffu + ((u >> 16) & 1u);   // round-to-nearest-even
  return (uint16_t)(u >> 16);
}
__device__ __forceinline__ float bf2f(uint16_t b) {
  return __uint_as_float(((uint32_t)b) << 16);
}

__device__ __forceinline__ void gload_lds16(const void* g, void* l) {
  __builtin_amdgcn_global_load_lds((const __attribute__((address_space(1))) void*)g,
                                   (__attribute__((address_space(3))) void*)l,
                                   16, 0, 0);
}

__device__ __forceinline__ int seg_of(int r) {
  // RANKS = [32,16,8,4,2,1] -> prefix 32,48,56,60,62,63
  return (r < 32) ? 0 : (r < 48) ? 1 : (r < 56) ? 2 : (r < 60) ? 3 : (r < 62) ? 4 : 5;
}

// ---------- split x (f32) into hi/lo bf16 ----------
__global__ void split_x_kernel(const float* __restrict__ x,
                               uint16_t* __restrict__ xh,
                               uint16_t* __restrict__ xl) {
  size_t i = (size_t)blockIdx.x * blockDim.x + threadIdx.x;  // one per 8 floats
  const float4* xv = (const float4*)x;
  float4 v0 = xv[2 * i];
  float4 v1 = xv[2 * i + 1];
  float v[8] = {v0.x, v0.y, v0.z, v0.w, v1.x, v1.y, v1.z, v1.w};
  u16x8 h, lo;
#pragma unroll
  for (int k = 0; k < 8; ++k) {
    uint16_t hb = f2bf_rn(v[k]);
    h[k] = hb;
    lo[k] = f2bf_rn(v[k] - bf2f(hb));
  }
  *(u16x8*)(xh + 8 * i) = h;
  *(u16x8*)(xl + 8 * i) = lo;
}

// ---------- W_eff = W_base + B diag(c) A, split into hi/lo bf16 ----------
__global__ void merge_w_kernel(const float* __restrict__ Wb,
                               const float* __restrict__ A,
                               const float* __restrict__ Bm,
                               const float* __restrict__ alphas,
                               const float* __restrict__ scalings,
                               uint16_t* __restrict__ wh,
                               uint16_t* __restrict__ wl) {
  const int o = blockIdx.x >> 2;
  const int i0 = ((blockIdx.x & 3) << 10) | (threadIdx.x << 2);
  __shared__ float brow[TOTAL_R];
  if (threadIdx.x < TOTAL_R) {
    int r = threadIdx.x;
    int s = seg_of(r);
    brow[r] = Bm[(size_t)o * TOTAL_R + r] * alphas[s] * scalings[s];
  }
  __syncthreads();
  const size_t base = (size_t)o * IN_F + i0;
  f32x4 acc = *(const f32x4*)(Wb + base);
#pragma unroll 7
  for (int r = 0; r < TOTAL_R; ++r) {
    f32x4 a = *(const f32x4*)(A + (size_t)r * IN_F + i0);
    acc += brow[r] * a;
  }
  u16x4 h, lo;
#pragma unroll
  for (int k = 0; k < 4; ++k) {
    uint16_t hb = f2bf_rn(acc[k]);
    h[k] = hb;
    lo[k] = f2bf_rn(acc[k] - bf2f(hb));
  }
  *(u16x4*)(wh + base) = h;
  *(u16x4*)(wl + base) = lo;
}

// ---------- fused split-bf16 GEMM, W-direct-from-L2, X in dbuf LDS ----------
// out = xh@wh^T + xl@wh^T + xh@wl^T + bias
// 128x128 tile, BK=32, 256 threads (4 waves 2x2), wave tile 64x64, 32x32x16.
// W fragments (lane holds row bcol+(l&31), 8 contig k at (2kh+khi)*8) are
// loaded DIRECTLY from global (L2-hot via bm-minor raster) into registers,
// double-buffered W0/W1 (static names), prefetched 1 K-step ahead.
// X staged in LDS (2 x 16KB dbuf, r2-verified pack+swizzle), counted
// vmcnt(12) = 4 X-stages + 8 W-loads in flight; raw barriers, no drain.
__global__ __launch_bounds__(256, 2) void gemm_mrlora(
    const uint16_t* __restrict__ xh, const uint16_t* __restrict__ xl,
    const uint16_t* __restrict__ wh, const uint16_t* __restrict__ wl,
    const float* __restrict__ bias, float* __restrict__ out) {
  __shared__ uint16_t sX[2][2][4096];   // [buf][hi/lo][128x32 packed]
  const int t = threadIdx.x;
  const int l = t & 63;
  const int w = t >> 6;
  const int wr = w >> 1, wc = w & 1;
  const int r31 = l & 31, khi = l >> 5;

  // raster: XCD chunk (256 blocks) covers 8 bm x 32 bn, bm-minor (W-panel L2-hot)
  const int xcd = blockIdx.x & 7;
  const int kk = blockIdx.x >> 3;
  const int bm = xcd * 8 + (kk & 7);
  const int bn = kk >> 3;
  const size_t brow = (size_t)bm * 128;
  const size_t bcol = (size_t)bn * 128;

  // X staging source map (thread t -> linear dest slot, pre-swizzled source)
  const int lrow = t >> 3;
  const int sp = (t & 7) ^ (lrow & 7);
  const int grow = lrow * 2 + (sp >> 2);
  const int gcol = (sp & 3) * 8;
  const uint16_t* pXh = xh + (brow + grow) * (size_t)IN_F + gcol;
  const uint16_t* pXl = xl + (brow + grow) * (size_t)IN_F + gcol;
  const int t8 = t * 8;

  // X fragment read offsets (elements): row (l&31), 16B slot 2*kh+khi
  int aoff[2][2];
#pragma unroll
  for (int mb = 0; mb < 2; ++mb)
#pragma unroll
    for (int kh = 0; kh < 2; ++kh) {
      int row = wr * 64 + mb * 32 + r31;
      int line = row >> 1;
      int slog = (row & 1) * 4 + 2 * kh + khi;
      aoff[mb][kh] = line * 64 + ((slog ^ (line & 7)) << 3);
    }

  // W direct-load bases: thread reads row (bcol + wc*64 + nb*32 + r31),
  // k = kt*32 + kh*16 + khi*8 (16B per load)
  const uint16_t* pWH = wh + (bcol + wc * 64 + r31) * (size_t)IN_F + khi * 8;
  const uint16_t* pWL = wl + (bcol + wc * 64 + r31) * (size_t)IN_F + khi * 8;

  bf16x8 W0h[2][2], W0l[2][2], W1h[2][2], W1l[2][2];
  f32x16 acc[2][2] = {};

#define STAGE(buf, ktv)                                          \
  do {                                                           \
    const int _k0 = (ktv) * 32;                                  \
    gload_lds16(pXh + _k0, &sX[buf][0][t8]);                     \
    gload_lds16(pXh + 64 * IN_F + _k0, &sX[buf][0][t8 + 2048]);  \
    gload_lds16(pXl + _k0, &sX[buf][1][t8]);                     \
    gload_lds16(pXl + 64 * IN_F + _k0, &sX[buf][1][t8 + 2048]);  \
  } while (0)

#define WLOAD(WH, WL, ktv)                                                  \
  do {                                                                      \
    const size_t _ko = (size_t)(ktv) * 32;                                  \
    WH[0][0] = *(const bf16x8*)(pWH + _ko);                                 \
    WH[0][1] = *(const bf16x8*)(pWH + _ko + 16);                            \
    WH[1][0] = *(const bf16x8*)(pWH + _ko + (size_t)32 * IN_F);             \
    WH[1][1] = *(const bf16x8*)(pWH + _ko + (size_t)32 * IN_F + 16);        \
    WL[0][0] = *(const bf16x8*)(pWL + _ko);                                 \
    WL[0][1] = *(const bf16x8*)(pWL + _ko + 16);                            \
    WL[1][0] = *(const bf16x8*)(pWL + _ko + (size_t)32 * IN_F);             \
    WL[1][1] = *(const bf16x8*)(pWL + _ko + (size_t)32 * IN_F + 16);        \
  } while (0)

#define COMPUTE(buf, WH, WL)                                                            \
  do {                                                                                  \
    bf16x8 _ah[2][2], _al[2][2];                                                        \
    _Pragma("unroll") for (int mb = 0; mb < 2; ++mb)                                    \
        _Pragma("unroll") for (int kh = 0; kh < 2; ++kh) {                              \
      _ah[mb][kh] = *(const bf16x8*)&sX[buf][0][aoff[mb][kh]];                          \
      _al[mb][kh] = *(const bf16x8*)&sX[buf][1][aoff[mb][kh]];                          \
    }                                                                                   \
    __builtin_amdgcn_s_setprio(1);                                                      \
    _Pragma("unroll") for (int kh = 0; kh < 2; ++kh)                                    \
        _Pragma("unroll") for (int mb = 0; mb < 2; ++mb)                                \
            _Pragma("unroll") for (int nb = 0; nb < 2; ++nb)                            \
      acc[mb][nb] = __builtin_amdgcn_mfma_f32_32x32x16_bf16(_ah[mb][kh], WH[nb][kh],    \
                                                            acc[mb][nb], 0, 0, 0);     \
    _Pragma("unroll") for (int kh = 0; kh < 2; ++kh)                                    \
        _Pragma("unroll") for (int mb = 0; mb < 2; ++mb)                                \
            _Pragma("unroll") for (int nb = 0; nb < 2; ++nb)                            \
      acc[mb][nb] = __builtin_amdgcn_mfma_f32_32x32x16_bf16(_al[mb][kh], WH[nb][kh],    \
                                                            acc[mb][nb], 0, 0, 0);     \
    _Pragma("unroll") for (int kh = 0; kh < 2; ++kh)                                    \
        _Pragma("unroll") for (int mb = 0; mb < 2; ++mb)                                \
            _Pragma("unroll") for (int nb = 0; nb < 2; ++nb)                            \
      acc[mb][nb] = __builtin_amdgcn_mfma_f32_32x32x16_bf16(_ah[mb][kh], WL[nb][kh],    \
                                                            acc[mb][nb], 0, 0, 0);     \
    __builtin_amdgcn_s_setprio(0);                                                      \
  } while (0)

  // prologue: tile 0 in flight (12 ops)
  STAGE(0, 0);
  WLOAD(W0h, W0l, 0);

  for (int p = 0; p < 64; ++p) {
    // ---- first half: compute kt=2p from buf0/W0; prefetch 2p+1 ----
    STAGE(1, 2 * p + 1);
    WLOAD(W1h, W1l, 2 * p + 1);
    asm volatile("s_waitcnt vmcnt(12)" ::: "memory");  // tile 2p fully landed
    __builtin_amdgcn_s_barrier();
    __builtin_amdgcn_sched_barrier(0);
    COMPUTE(0, W0h, W0l);
    __builtin_amdgcn_sched_barrier(0);
    __builtin_amdgcn_s_barrier();      // buf0 reads done before restage

    // ---- second half: compute kt=2p+1 from buf1/W1; prefetch 2p+2 ----
    if (p < 63) {
      STAGE(0, 2 * p + 2);
      WLOAD(W0h, W0l, 2 * p + 2);
      asm volatile("s_waitcnt vmcnt(12)" ::: "memory");  // tile 2p+1 landed
    } else {
      asm volatile("s_waitcnt vmcnt(0)" ::: "memory");
    }
    __builtin_amdgcn_s_barrier();
    __builtin_amdgcn_sched_barrier(0);
    COMPUTE(1, W1h, W1l);
    __builtin_amdgcn_sched_barrier(0);
    __builtin_amdgcn_s_barrier();      // buf1 reads done before restage
  }
#undef STAGE
#undef WLOAD
#undef COMPUTE

  // epilogue: C/D 32x32 layout col = lane&31, row = (reg&3)+8*(reg>>2)+4*(lane>>5)
#pragma unroll
  for (int nb = 0; nb < 2; ++nb) {
    const size_t col = bcol + wc * 64 + nb * 32 + r31;
    const float bs = bias[col];
#pragma unroll
    for (int mb = 0; mb < 2; ++mb) {
      const size_t row0 = brow + wr * 64 + mb * 32 + 4 * khi;
#pragma unroll
      for (int r = 0; r < 16; ++r) {
        const size_t row = row0 + (r & 3) + 8 * (r >> 2);
        out[row * OUT_F + col] = acc[mb][nb][r] + bs;
      }
    }
  }
}

// ================= fallback path (small workspace): fp32 =================

__global__ __launch_bounds__(256) void fb_z_kernel(const float* __restrict__ x,
                                                   const float* __restrict__ A,
                                                   const float* __restrict__ alphas,
                                                   const float* __restrict__ scalings,
                                                   float* __restrict__ z) {
  __shared__ float sx[IN_F];
  __shared__ float red[256];
  const int m = blockIdx.x, t = threadIdx.x;
  for (int i = t; i < IN_F / 4; i += 256)
    ((float4*)sx)[i] = ((const float4*)(x + (size_t)m * IN_F))[i];
  __syncthreads();
  const int r = t >> 2, q = t & 3;
  float part = 0.f;
  if (r < TOTAL_R) {
    const float4* Ar = (const float4*)(A + (size_t)r * IN_F + q * 1024);
    const float4* xs = (const float4*)(sx + q * 1024);
    for (int k = 0; k < 256; ++k) {
      float4 av = Ar[k], xv = xs[k];
      part += av.x * xv.x + av.y * xv.y + av.z * xv.z + av.w * xv.w;
    }
  }
  red[t] = part;
  __syncthreads();
  if (q == 0 && r < TOTAL_R) {
    int s = seg_of(r);
    z[(size_t)m * TOTAL_R + r] =
        alphas[s] * scalings[s] * (red[t] + red[t + 1] + red[t + 2] + red[t + 3]);
  }
}

__global__ __launch_bounds__(256) void fb_gemm_fp32(const float* __restrict__ x,
                                                    const float* __restrict__ Wb,
                                                    const float* __restrict__ bb,
                                                    const float* __restrict__ Bm,
                                                    const float* __restrict__ z,
                                                    float* __restrict__ out) {
  __shared__ float sx[64][33];
  __shared__ float sw[64][33];
  const int t = threadIdx.x;
  const int tr = t >> 4, tc = t & 15;
  const int bm = blockIdx.x / (OUT_F / 64);
  const int bn = blockIdx.x % (OUT_F / 64);
  const size_t brow = (size_t)bm * 64, bcol = (size_t)bn * 64;
  const int r = t >> 2, c0 = (t & 3) * 8;
  float acc[4][4] = {};
  for (int k0 = 0; k0 < IN_F; k0 += 32) {
    float4 a0 = *(const float4*)(x + (brow + r) * IN_F + k0 + c0);
    float4 a1 = *(const float4*)(x + (brow + r) * IN_F + k0 + c0 + 4);
    float4 w0 = *(const float4*)(Wb + (bcol + r) * IN_F + k0 + c0);
    float4 w1 = *(const float4*)(Wb + (bcol + r) * IN_F + k0 + c0 + 4);
    __syncthreads();
    sx[r][c0 + 0] = a0.x; sx[r][c0 + 1] = a0.y; sx[r][c0 + 2] = a0.z; sx[r][c0 + 3] = a0.w;
    sx[r][c0 + 4] = a1.x; sx[r][c0 + 5] = a1.y; sx[r][c0 + 6] = a1.z; sx[r][c0 + 7] = a1.w;
    sw[r][c0 + 0] = w0.x; sw[r][c0 + 1] = w0.y; sw[r][c0 + 2] = w0.z; sw[r][c0 + 3] = w0.w;
    sw[r][c0 + 4] = w1.x; sw[r][c0 + 5] = w1.y; sw[r][c0 + 6] = w1.z; sw[r][c0 + 7] = w1.w;
    __syncthreads();
#pragma unroll
    for (int k = 0; k < 32; ++k) {
      float xa[4], wv[4];
#pragma unroll
      for (int i = 0; i < 4; ++i) xa[i] = sx[tr + 16 * i][k];
#pragma unroll
      for (int j = 0; j < 4; ++j) wv[j] = sw[tc + 16 * j][k];
#pragma unroll
      for (int i = 0; i < 4; ++i)
#pragma unroll
        for (int j = 0; j < 4; ++j) acc[i][j] += xa[i] * wv[j];
    }
  }
#pragma unroll 1
  for (int rr = 0; rr < TOTAL_R; ++rr) {
    float zr[4], br[4];
#pragma unroll
    for (int i = 0; i < 4; ++i) zr[i] = z[(brow + tr + 16 * i) * TOTAL_R + rr];
#pragma unroll
    for (int j = 0; j < 4; ++j) br[j] = Bm[(bcol + tc + 16 * j) * TOTAL_R + rr];
#pragma unroll
    for (int i = 0; i < 4; ++i)
#pragma unroll
      for (int j = 0; j < 4; ++j) acc[i][j] += zr[i] * br[j];
  }
#pragma unroll
  for (int i = 0; i < 4; ++i)
#pragma unroll
    for (int j = 0; j < 4; ++j) {
      size_t row = brow + tr + 16 * i, col = bcol + tc + 16 * j;
      out[row * OUT_F + col] = acc[i][j] + bb[col];
    }
}

extern "C" void kernel_launch(void* const* d_in, const int* in_sizes, int n_in,
                              void* d_out, int out_size, void* d_ws, size_t ws_size,
                              hipStream_t stream) {
  const float* x  = (const float*)d_in[0];
  const float* Wb = (const float*)d_in[1];
  const float* bb = (const float*)d_in[2];
  const float* A  = (const float*)d_in[3];
  const float* Bm = (const float*)d_in[4];
  const float* al = (const float*)d_in[5];
  const float* sc = (const float*)d_in[6];
  float* out = (float*)d_out;

  const size_t MB = (size_t)1 << 20;
  if (ws_size >= 192 * MB) {
    char* ws = (char*)d_ws;
    uint16_t* xh = (uint16_t*)(ws);
    uint16_t* xl = (uint16_t*)(ws + 64 * MB);
    uint16_t* wh = (uint16_t*)(ws + 128 * MB);
    uint16_t* wl = (uint16_t*)(ws + 160 * MB);
    split_x_kernel<<<(M_TOT * IN_F / 8) / 256, 256, 0, stream>>>(x, xh, xl);
    merge_w_kernel<<<OUT_F * 4, 256, 0, stream>>>(Wb, A, Bm, al, sc, wh, wl);
    gemm_mrlora<<<2048, 256, 0, stream>>>(xh, xl, wh, wl, bb, out);
  } else {
    float* z = (float*)d_ws;  // needs 8192*63*4 ~= 2 MB
    fb_z_kernel<<<M_TOT, 256, 0, stream>>>(x, A, al, sc, z);
    fb_gemm_fp32<<<(M_TOT / 64) * (OUT_F / 64), 256, 0, stream>>>(x, Wb, bb, Bm, z, out);
  }
}

// Round 6
// 518.655 us; speedup vs baseline: 2.6580x; 2.6580x over previous
//
#include <hip/hip_runtime.h>
#include <hip/hip_fp16.h>
#include <cstdint>

#define IN_F 4096
#define OUT_F 4096
#define M_TOT 8192     // BATCH*SEQ = 4*2048
#define TOTAL_R 63

typedef __attribute__((ext_vector_type(8))) _Float16 f16x8;
typedef __attribute__((ext_vector_type(4))) float f32x4;
typedef __attribute__((ext_vector_type(16))) float f32x16;
typedef __attribute__((ext_vector_type(8))) unsigned short u16x8;
typedef __attribute__((ext_vector_type(4))) unsigned short u16x4;

__device__ __forceinline__ void gload_lds16(const void* g, void* l) {
  __builtin_amdgcn_global_load_lds((const __attribute__((address_space(1))) void*)g,
                                   (__attribute__((address_space(3))) void*)l,
                                   16, 0, 0);
}

__device__ __forceinline__ int seg_of(int r) {
  // RANKS = [32,16,8,4,2,1] -> prefix 32,48,56,60,62,63
  return (r < 32) ? 0 : (r < 48) ? 1 : (r < 56) ? 2 : (r < 60) ? 3 : (r < 62) ? 4 : 5;
}

// ---------- convert x (f32) to fp16 ----------
__global__ void conv_x_f16(const float* __restrict__ x, uint16_t* __restrict__ xh) {
  size_t i = (size_t)blockIdx.x * blockDim.x + threadIdx.x;  // one per 8 floats
  const float4* xv = (const float4*)x;
  float4 v0 = xv[2 * i];
  float4 v1 = xv[2 * i + 1];
  float v[8] = {v0.x, v0.y, v0.z, v0.w, v1.x, v1.y, v1.z, v1.w};
  u16x8 h;
#pragma unroll
  for (int k = 0; k < 8; ++k) h[k] = __half_as_ushort(__float2half_rn(v[k]));
  *(u16x8*)(xh + 8 * i) = h;
}

// ---------- W_eff = W_base + B diag(c) A, to fp16 ----------
__global__ void merge_w_kernel(const float* __restrict__ Wb,
                               const float* __restrict__ A,
                               const float* __restrict__ Bm,
                               const float* __restrict__ alphas,
                               const float* __restrict__ scalings,
                               uint16_t* __restrict__ wh) {
  const int o = blockIdx.x >> 2;
  const int i0 = ((blockIdx.x & 3) << 10) | (threadIdx.x << 2);
  __shared__ float brow[TOTAL_R];
  if (threadIdx.x < TOTAL_R) {
    int r = threadIdx.x;
    int s = seg_of(r);
    brow[r] = Bm[(size_t)o * TOTAL_R + r] * alphas[s] * scalings[s];
  }
  __syncthreads();
  const size_t base = (size_t)o * IN_F + i0;
  f32x4 acc = *(const f32x4*)(Wb + base);
#pragma unroll 7
  for (int r = 0; r < TOTAL_R; ++r) {
    f32x4 a = *(const f32x4*)(A + (size_t)r * IN_F + i0);
    acc += brow[r] * a;
  }
  u16x4 h;
#pragma unroll
  for (int k = 0; k < 4; ++k) h[k] = __half_as_ushort(__float2half_rn(acc[k]));
  *(u16x4*)(wh + base) = h;
}

// ---------- single-product fp16 GEMM: out = xh @ wh^T + bias ----------
// 128x128 tile, BK=64, 256 threads (4 waves 2x2), wave tile 64x64,
// mfma_f32_32x32x16_f16. Proven r2/r4 sync structure: single-buffer LDS,
// gload_lds staging, 2 __syncthreads per K-step, bm-minor XCD raster.
// LDS per stream: 128 rows x 64 halfs = 128 lines x 8 x 16B slots (16KB);
// slot swizzle phys = slog ^ (line&7) applied on the pre-swizzled global
// SOURCE addr (gload_lds dest linear, rule 21) and on the ds_read addr.
__global__ __launch_bounds__(256) void gemm_mrlora(
    const uint16_t* __restrict__ xh, const uint16_t* __restrict__ wh,
    const float* __restrict__ bias, float* __restrict__ out) {
  __shared__ uint16_t sX[8192];   // 16KB
  __shared__ uint16_t sW[8192];   // 16KB
  const int t = threadIdx.x;
  const int l = t & 63;
  const int w = t >> 6;
  const int wr = w >> 1, wc = w & 1;
  const int r31 = l & 31, khi = l >> 5;

  // raster: XCD chunk (256 blocks) covers 8 bm x 32 bn, bm-minor (W-panel L2-hot)
  const int xcd = blockIdx.x & 7;
  const int kk = blockIdx.x >> 3;
  const int bm = xcd * 8 + (kk & 7);
  const int bn = kk >> 3;
  const size_t brow = (size_t)bm * 128;
  const size_t bcol = (size_t)bn * 128;

  // staging: 1024 slots/stream, thread t + gload g covers slot S = g*256+t.
  // line = S>>3 = g*32 + (t>>3); phys slot = S&7 = t&7; source logical slot
  // slog = (t&7) ^ (line&7) = (t&7) ^ ((t>>3)&7)  (g*32 is 0 mod 8).
  const int lrow = t >> 3;
  const int sp = (t & 7) ^ (lrow & 7);
  const uint16_t* pX = xh + (brow + lrow) * (size_t)IN_F + sp * 8;
  const uint16_t* pW = wh + (bcol + lrow) * (size_t)IN_F + sp * 8;
  const int t8 = t * 8;

  // fragment read offsets (halfs): row r at line r, 16B slot (2*kh+khi),
  // phys = slog ^ (r&7)
  int aoff[2][4], boff[2][4];
#pragma unroll
  for (int mb = 0; mb < 2; ++mb)
#pragma unroll
    for (int kh = 0; kh < 4; ++kh) {
      int row = wr * 64 + mb * 32 + r31;
      int slog = 2 * kh + khi;
      aoff[mb][kh] = row * 64 + (((slog ^ (row & 7))) << 3);
      row = wc * 64 + mb * 32 + r31;
      boff[mb][kh] = row * 64 + (((slog ^ (row & 7))) << 3);
    }

  f32x16 acc[2][2] = {};

  for (int kt = 0; kt < IN_F / 64; ++kt) {
    const int k0 = kt * 64;
#pragma unroll
    for (int g = 0; g < 4; ++g) {
      gload_lds16(pX + (size_t)32 * g * IN_F + k0, &sX[t8 + g * 2048]);
      gload_lds16(pW + (size_t)32 * g * IN_F + k0, &sW[t8 + g * 2048]);
    }
    __syncthreads();  // compiler drains vmcnt before barrier

    f16x8 af[2][4], bf[2][4];
#pragma unroll
    for (int mb = 0; mb < 2; ++mb)
#pragma unroll
      for (int kh = 0; kh < 4; ++kh) {
        af[mb][kh] = *(const f16x8*)&sX[aoff[mb][kh]];
        bf[mb][kh] = *(const f16x8*)&sW[boff[mb][kh]];
      }

#pragma unroll
    for (int kh = 0; kh < 4; ++kh)
#pragma unroll
      for (int mb = 0; mb < 2; ++mb)
#pragma unroll
        for (int nb = 0; nb < 2; ++nb)
          acc[mb][nb] = __builtin_amdgcn_mfma_f32_32x32x16_f16(af[mb][kh], bf[nb][kh], acc[mb][nb], 0, 0, 0);

    __syncthreads();  // reads done before next-tile overwrite
  }

  // epilogue: C/D 32x32 layout col = lane&31, row = (reg&3)+8*(reg>>2)+4*(lane>>5)
#pragma unroll
  for (int nb = 0; nb < 2; ++nb) {
    const size_t col = bcol + wc * 64 + nb * 32 + r31;
    const float bs = bias[col];
#pragma unroll
    for (int mb = 0; mb < 2; ++mb) {
      const size_t row0 = brow + wr * 64 + mb * 32 + 4 * khi;
#pragma unroll
      for (int r = 0; r < 16; ++r) {
        const size_t row = row0 + (r & 3) + 8 * (r >> 2);
        out[row * OUT_F + col] = acc[mb][nb][r] + bs;
      }
    }
  }
}

// ================= fallback path (small workspace): fp32 =================

__global__ __launch_bounds__(256) void fb_z_kernel(const float* __restrict__ x,
                                                   const float* __restrict__ A,
                                                   const float* __restrict__ alphas,
                                                   const float* __restrict__ scalings,
                                                   float* __restrict__ z) {
  __shared__ float sx[IN_F];
  __shared__ float red[256];
  const int m = blockIdx.x, t = threadIdx.x;
  for (int i = t; i < IN_F / 4; i += 256)
    ((float4*)sx)[i] = ((const float4*)(x + (size_t)m * IN_F))[i];
  __syncthreads();
  const int r = t >> 2, q = t & 3;
  float part = 0.f;
  if (r < TOTAL_R) {
    const float4* Ar = (const float4*)(A + (size_t)r * IN_F + q * 1024);
    const float4* xs = (const float4*)(sx + q * 1024);
    for (int k = 0; k < 256; ++k) {
      float4 av = Ar[k], xv = xs[k];
      part += av.x * xv.x + av.y * xv.y + av.z * xv.z + av.w * xv.w;
    }
  }
  red[t] = part;
  __syncthreads();
  if (q == 0 && r < TOTAL_R) {
    int s = seg_of(r);
    z[(size_t)m * TOTAL_R + r] =
        alphas[s] * scalings[s] * (red[t] + red[t + 1] + red[t + 2] + red[t + 3]);
  }
}

__global__ __launch_bounds__(256) void fb_gemm_fp32(const float* __restrict__ x,
                                                    const float* __restrict__ Wb,
                                                    const float* __restrict__ bb,
                                                    const float* __restrict__ Bm,
                                                    const float* __restrict__ z,
                                                    float* __restrict__ out) {
  __shared__ float sx[64][33];
  __shared__ float sw[64][33];
  const int t = threadIdx.x;
  const int tr = t >> 4, tc = t & 15;
  const int bm = blockIdx.x / (OUT_F / 64);
  const int bn = blockIdx.x % (OUT_F / 64);
  const size_t brow = (size_t)bm * 64, bcol = (size_t)bn * 64;
  const int r = t >> 2, c0 = (t & 3) * 8;
  float acc[4][4] = {};
  for (int k0 = 0; k0 < IN_F; k0 += 32) {
    float4 a0 = *(const float4*)(x + (brow + r) * IN_F + k0 + c0);
    float4 a1 = *(const float4*)(x + (brow + r) * IN_F + k0 + c0 + 4);
    float4 w0 = *(const float4*)(Wb + (bcol + r) * IN_F + k0 + c0);
    float4 w1 = *(const float4*)(Wb + (bcol + r) * IN_F + k0 + c0 + 4);
    __syncthreads();
    sx[r][c0 + 0] = a0.x; sx[r][c0 + 1] = a0.y; sx[r][c0 + 2] = a0.z; sx[r][c0 + 3] = a0.w;
    sx[r][c0 + 4] = a1.x; sx[r][c0 + 5] = a1.y; sx[r][c0 + 6] = a1.z; sx[r][c0 + 7] = a1.w;
    sw[r][c0 + 0] = w0.x; sw[r][c0 + 1] = w0.y; sw[r][c0 + 2] = w0.z; sw[r][c0 + 3] = w0.w;
    sw[r][c0 + 4] = w1.x; sw[r][c0 + 5] = w1.y; sw[r][c0 + 6] = w1.z; sw[r][c0 + 7] = w1.w;
    __syncthreads();
#pragma unroll
    for (int k = 0; k < 32; ++k) {
      float xa[4], wv[4];
#pragma unroll
      for (int i = 0; i < 4; ++i) xa[i] = sx[tr + 16 * i][k];
#pragma unroll
      for (int j = 0; j < 4; ++j) wv[j] = sw[tc + 16 * j][k];
#pragma unroll
      for (int i = 0; i < 4; ++i)
#pragma unroll
        for (int j = 0; j < 4; ++j) acc[i][j] += xa[i] * wv[j];
    }
  }
#pragma unroll 1
  for (int rr = 0; rr < TOTAL_R; ++rr) {
    float zr[4], br[4];
#pragma unroll
    for (int i = 0; i < 4; ++i) zr[i] = z[(brow + tr + 16 * i) * TOTAL_R + rr];
#pragma unroll
    for (int j = 0; j < 4; ++j) br[j] = Bm[(bcol + tc + 16 * j) * TOTAL_R + rr];
#pragma unroll
    for (int i = 0; i < 4; ++i)
#pragma unroll
      for (int j = 0; j < 4; ++j) acc[i][j] += zr[i] * br[j];
  }
#pragma unroll
  for (int i = 0; i < 4; ++i)
#pragma unroll
    for (int j = 0; j < 4; ++j) {
      size_t row = brow + tr + 16 * i, col = bcol + tc + 16 * j;
      out[row * OUT_F + col] = acc[i][j] + bb[col];
    }
}

extern "C" void kernel_launch(void* const* d_in, const int* in_sizes, int n_in,
                              void* d_out, int out_size, void* d_ws, size_t ws_size,
                              hipStream_t stream) {
  const float* x  = (const float*)d_in[0];
  const float* Wb = (const float*)d_in[1];
  const float* bb = (const float*)d_in[2];
  const float* A  = (const float*)d_in[3];
  const float* Bm = (const float*)d_in[4];
  const float* al = (const float*)d_in[5];
  const float* sc = (const float*)d_in[6];
  float* out = (float*)d_out;

  const size_t MB = (size_t)1 << 20;
  if (ws_size >= 96 * MB) {
    char* ws = (char*)d_ws;
    uint16_t* xh = (uint16_t*)(ws);             // 64 MB fp16
    uint16_t* wh = (uint16_t*)(ws + 64 * MB);   // 32 MB fp16
    conv_x_f16<<<(M_TOT * IN_F / 8) / 256, 256, 0, stream>>>(x, xh);
    merge_w_kernel<<<OUT_F * 4, 256, 0, stream>>>(Wb, A, Bm, al, sc, wh);
    gemm_mrlora<<<2048, 256, 0, stream>>>(xh, wh, bb, out);
  } else {
    float* z = (float*)d_ws;  // needs 8192*63*4 ~= 2 MB
    fb_z_kernel<<<M_TOT, 256, 0, stream>>>(x, A, al, sc, z);
    fb_gemm_fp32<<<(M_TOT / 64) * (OUT_F / 64), 256, 0, stream>>>(x, Wb, bb, Bm, z, out);
  }
}

// Round 7
// 404.939 us; speedup vs baseline: 3.4045x; 1.2808x over previous
//
#include <hip/hip_runtime.h>
#include <hip/hip_fp16.h>
#include <cstdint>

#define IN_F 4096
#define OUT_F 4096
#define M_TOT 8192     // BATCH*SEQ = 4*2048
#define TOTAL_R 63

typedef __attribute__((ext_vector_type(8))) _Float16 f16x8;
typedef __attribute__((ext_vector_type(4))) float f32x4;
typedef __attribute__((ext_vector_type(8))) unsigned short u16x8;
typedef __attribute__((ext_vector_type(4))) unsigned short u16x4;

__device__ __forceinline__ void gload_lds16(const void* g, void* l) {
  __builtin_amdgcn_global_load_lds((const __attribute__((address_space(1))) void*)g,
                                   (__attribute__((address_space(3))) void*)l,
                                   16, 0, 0);
}

__device__ __forceinline__ int seg_of(int r) {
  // RANKS = [32,16,8,4,2,1] -> prefix 32,48,56,60,62,63
  return (r < 32) ? 0 : (r < 48) ? 1 : (r < 56) ? 2 : (r < 60) ? 3 : (r < 62) ? 4 : 5;
}

// ---------- convert x (f32) to fp16 ----------
__global__ void conv_x_f16(const float* __restrict__ x, uint16_t* __restrict__ xh) {
  size_t i = (size_t)blockIdx.x * blockDim.x + threadIdx.x;  // one per 8 floats
  const float4* xv = (const float4*)x;
  float4 v0 = xv[2 * i];
  float4 v1 = xv[2 * i + 1];
  float v[8] = {v0.x, v0.y, v0.z, v0.w, v1.x, v1.y, v1.z, v1.w};
  u16x8 h;
#pragma unroll
  for (int k = 0; k < 8; ++k) h[k] = __half_as_ushort(__float2half_rn(v[k]));
  *(u16x8*)(xh + 8 * i) = h;
}

// ---------- W_eff = W_base + B diag(c) A, to fp16 (v2: 64o x 256i per block) ----------
// Fix for r6's 4.2GB L2 traffic: A-tile [63][256] f32 staged in LDS ONCE per
// block (64 MB total A-traffic), read by all 64 o's via same-address broadcast
// (free). Scaled B^T [63][64] in LDS, read at lane-stride-1 (free).
__global__ __launch_bounds__(256) void merge_w_kernel(
    const float* __restrict__ Wb, const float* __restrict__ A,
    const float* __restrict__ Bm, const float* __restrict__ alphas,
    const float* __restrict__ scalings, uint16_t* __restrict__ wh) {
  __shared__ float sA[63 * 256];   // 63 KB
  __shared__ float sBT[63 * 64];   // 15.75 KB
  const int t = threadIdx.x;
  const int bo = blockIdx.x >> 4, bi = blockIdx.x & 15;
  const int o0 = bo * 64, i0 = bi * 256;
  const int wv = t >> 6, ln = t & 63;

  // stage A: linear per-wave copy; iteration k: wave wv writes row r = k*4+wv
  // (one 1KB row per wave, lanes coalesced f32x4), skip r=63.
#pragma unroll
  for (int k = 0; k < 16; ++k) {
    int r = k * 4 + wv;
    if (r < 63) {
      f32x4 v = *(const f32x4*)(A + (size_t)r * IN_F + i0 + ln * 4);
      *(f32x4*)(sA + r * 256 + ln * 4) = v;
    }
  }
  // stage scaled B^T: sBT[r*64+oo] = B[o0+oo][r] * alpha*scaling
  {
    const int oo = ln;
    const int rbase = wv * 16;
#pragma unroll
    for (int rr = 0; rr < 16; ++rr) {
      int r = rbase + rr;
      if (r < 63) {
        int s = seg_of(r);
        sBT[r * 64 + oo] = Bm[(size_t)(o0 + oo) * TOTAL_R + r] * alphas[s] * scalings[s];
      }
    }
  }
  __syncthreads();

  const int oo = t & 63, iq = t >> 6;   // thread: one o, 64 i's
  const size_t obase = (size_t)(o0 + oo) * IN_F + i0 + iq * 64;
  f32x4 acc4[16];
#pragma unroll
  for (int v = 0; v < 16; ++v) acc4[v] = *(const f32x4*)(Wb + obase + v * 4);
#pragma unroll 9
  for (int r = 0; r < 63; ++r) {
    const float coeff = sBT[r * 64 + oo];           // lane-stride-1: free
    const f32x4* ar = (const f32x4*)(sA + r * 256 + iq * 64);  // broadcast: free
#pragma unroll
    for (int v = 0; v < 16; ++v) acc4[v] += coeff * ar[v];
  }
#pragma unroll
  for (int v = 0; v < 16; ++v) {
    u16x4 h;
#pragma unroll
    for (int k = 0; k < 4; ++k) h[k] = __half_as_ushort(__float2half_rn(acc4[v][k]));
    *(u16x4*)(wh + obase + v * 4) = h;
  }
}

// ---------- single-product fp16 GEMM: out = xh @ wh^T + bias ----------
// 256x128 block tile, BK=32, 256 threads (4 waves 2Mx2N), wave tile 128x64,
// mfma_f32_16x16x32_f16 (16-row fragment pattern = r2's measured-ZERO-conflict
// LDS pattern; the 32-row pattern costs 4 cyc/read, r4/r5/r6). Proven 2-barrier
// sync. LDS: A 256x32 (16KB) + B 128x32 (8KB) fp16, packed 2 rows per 128B
// line (8 x 16B slots), slot swizzle phys = slog ^ (line&7) applied on the
// pre-swizzled global SOURCE (gload_lds dest linear, rule 21) and on ds_read.
// Per wave-K-step: 12 ds_read_b128 feed 32 MFMA -> LDS pipe 123us/CU < MFMA
// 132us/CU: first matrix-bound config.
__global__ __launch_bounds__(256, 2) void gemm_mrlora(
    const uint16_t* __restrict__ xh, const uint16_t* __restrict__ wh,
    const float* __restrict__ bias, float* __restrict__ out) {
  __shared__ uint16_t sX[8192];   // 256x32 fp16, 16KB
  __shared__ uint16_t sW[4096];   // 128x32 fp16, 8KB
  const int t = threadIdx.x;
  const int l = t & 63;
  const int w = t >> 6;
  const int wr = w >> 1, wc = w & 1;     // wave tile: rows wr*128, cols wc*64
  const int lr = l & 15, lg = l >> 4;

  // raster: XCD chunk (128 blocks) covers 4 bm x 32 bn, bm-minor (W-panel L2-hot)
  const int xcd = blockIdx.x & 7;
  const int kk = blockIdx.x >> 3;        // 0..127
  const int bm = xcd * 4 + (kk & 3);     // 0..31
  const int bn = kk >> 2;                // 0..31
  const size_t brow = (size_t)bm * 256;
  const size_t bcol = (size_t)bn * 128;

  // staging source map (r2): chunk D = g*256 + t -> line D>>3, phys D&7;
  // slog = (t&7)^((t>>3)&7); row = g*64 + (t>>3)*2 + (slog>>2); col = (slog&3)*8
  const int lrow = t >> 3;
  const int sp = (t & 7) ^ (lrow & 7);
  const int grow = lrow * 2 + (sp >> 2);
  const int gcol = (sp & 3) * 8;
  const uint16_t* pX = xh + (brow + grow) * (size_t)IN_F + gcol;
  const uint16_t* pW = wh + (bcol + grow) * (size_t)IN_F + gcol;
  const int t8 = t * 8;

  // fragment read offsets (halfs): row -> line=row>>1, slog=(row&1)*4+lg,
  // phys = slog ^ (line&7)  [r2's zero-conflict formula]
  int aoff[8], boff[4];
#pragma unroll
  for (int i = 0; i < 8; ++i) {
    int row = wr * 128 + i * 16 + lr;
    aoff[i] = (row >> 1) * 64 + (((((row & 1) << 2) | lg) ^ ((row >> 1) & 7)) << 3);
  }
#pragma unroll
  for (int j = 0; j < 4; ++j) {
    int row = wc * 64 + j * 16 + lr;
    boff[j] = (row >> 1) * 64 + (((((row & 1) << 2) | lg) ^ ((row >> 1) & 7)) << 3);
  }

  f32x4 acc[8][4] = {};

  for (int kt = 0; kt < IN_F / 32; ++kt) {
    const int k0 = kt * 32;
#pragma unroll
    for (int g = 0; g < 4; ++g)
      gload_lds16(pX + (size_t)(64 * g) * IN_F + k0, &sX[t8 + g * 2048]);
#pragma unroll
    for (int g = 0; g < 2; ++g)
      gload_lds16(pW + (size_t)(64 * g) * IN_F + k0, &sW[t8 + g * 2048]);
    __syncthreads();  // compiler drains vmcnt before barrier

    f16x8 af[8], bf[4];
#pragma unroll
    for (int i = 0; i < 8; ++i) af[i] = *(const f16x8*)&sX[aoff[i]];
#pragma unroll
    for (int j = 0; j < 4; ++j) bf[j] = *(const f16x8*)&sW[boff[j]];

#pragma unroll
    for (int i = 0; i < 8; ++i)
#pragma unroll
      for (int j = 0; j < 4; ++j)
        acc[i][j] = __builtin_amdgcn_mfma_f32_16x16x32_f16(af[i], bf[j], acc[i][j], 0, 0, 0);

    __syncthreads();  // reads done before next-tile overwrite
  }

  // epilogue: D layout col = lane&15, row = (lane>>4)*4 + reg
#pragma unroll
  for (int j = 0; j < 4; ++j) {
    const size_t col = bcol + wc * 64 + j * 16 + lr;
    const float bs = bias[col];
#pragma unroll
    for (int i = 0; i < 8; ++i) {
      const size_t row0 = brow + wr * 128 + i * 16 + lg * 4;
#pragma unroll
      for (int r = 0; r < 4; ++r)
        out[(row0 + r) * OUT_F + col] = acc[i][j][r] + bs;
    }
  }
}

// ================= fallback path (small workspace): fp32 =================

__global__ __launch_bounds__(256) void fb_z_kernel(const float* __restrict__ x,
                                                   const float* __restrict__ A,
                                                   const float* __restrict__ alphas,
                                                   const float* __restrict__ scalings,
                                                   float* __restrict__ z) {
  __shared__ float sx[IN_F];
  __shared__ float red[256];
  const int m = blockIdx.x, t = threadIdx.x;
  for (int i = t; i < IN_F / 4; i += 256)
    ((float4*)sx)[i] = ((const float4*)(x + (size_t)m * IN_F))[i];
  __syncthreads();
  const int r = t >> 2, q = t & 3;
  float part = 0.f;
  if (r < TOTAL_R) {
    const float4* Ar = (const float4*)(A + (size_t)r * IN_F + q * 1024);
    const float4* xs = (const float4*)(sx + q * 1024);
    for (int k = 0; k < 256; ++k) {
      float4 av = Ar[k], xv = xs[k];
      part += av.x * xv.x + av.y * xv.y + av.z * xv.z + av.w * xv.w;
    }
  }
  red[t] = part;
  __syncthreads();
  if (q == 0 && r < TOTAL_R) {
    int s = seg_of(r);
    z[(size_t)m * TOTAL_R + r] =
        alphas[s] * scalings[s] * (red[t] + red[t + 1] + red[t + 2] + red[t + 3]);
  }
}

__global__ __launch_bounds__(256) void fb_gemm_fp32(const float* __restrict__ x,
                                                    const float* __restrict__ Wb,
                                                    const float* __restrict__ bb,
                                                    const float* __restrict__ Bm,
                                                    const float* __restrict__ z,
                                                    float* __restrict__ out) {
  __shared__ float sx[64][33];
  __shared__ float sw[64][33];
  const int t = threadIdx.x;
  const int tr = t >> 4, tc = t & 15;
  const int bm = blockIdx.x / (OUT_F / 64);
  const int bn = blockIdx.x % (OUT_F / 64);
  const size_t brow = (size_t)bm * 64, bcol = (size_t)bn * 64;
  const int r = t >> 2, c0 = (t & 3) * 8;
  float acc[4][4] = {};
  for (int k0 = 0; k0 < IN_F; k0 += 32) {
    float4 a0 = *(const float4*)(x + (brow + r) * IN_F + k0 + c0);
    float4 a1 = *(const float4*)(x + (brow + r) * IN_F + k0 + c0 + 4);
    float4 w0 = *(const float4*)(Wb + (bcol + r) * IN_F + k0 + c0);
    float4 w1 = *(const float4*)(Wb + (bcol + r) * IN_F + k0 + c0 + 4);
    __syncthreads();
    sx[r][c0 + 0] = a0.x; sx[r][c0 + 1] = a0.y; sx[r][c0 + 2] = a0.z; sx[r][c0 + 3] = a0.w;
    sx[r][c0 + 4] = a1.x; sx[r][c0 + 5] = a1.y; sx[r][c0 + 6] = a1.z; sx[r][c0 + 7] = a1.w;
    sw[r][c0 + 0] = w0.x; sw[r][c0 + 1] = w0.y; sw[r][c0 + 2] = w0.z; sw[r][c0 + 3] = w0.w;
    sw[r][c0 + 4] = w1.x; sw[r][c0 + 5] = w1.y; sw[r][c0 + 6] = w1.z; sw[r][c0 + 7] = w1.w;
    __syncthreads();
#pragma unroll
    for (int k = 0; k < 32; ++k) {
      float xa[4], wv[4];
#pragma unroll
      for (int i = 0; i < 4; ++i) xa[i] = sx[tr + 16 * i][k];
#pragma unroll
      for (int j = 0; j < 4; ++j) wv[j] = sw[tc + 16 * j][k];
#pragma unroll
      for (int i = 0; i < 4; ++i)
#pragma unroll
        for (int j = 0; j < 4; ++j) acc[i][j] += xa[i] * wv[j];
    }
  }
#pragma unroll 1
  for (int rr = 0; rr < TOTAL_R; ++rr) {
    float zr[4], br[4];
#pragma unroll
    for (int i = 0; i < 4; ++i) zr[i] = z[(brow + tr + 16 * i) * TOTAL_R + rr];
#pragma unroll
    for (int j = 0; j < 4; ++j) br[j] = Bm[(bcol + tc + 16 * j) * TOTAL_R + rr];
#pragma unroll
    for (int i = 0; i < 4; ++i)
#pragma unroll
      for (int j = 0; j < 4; ++j) acc[i][j] += zr[i] * br[j];
  }
#pragma unroll
  for (int i = 0; i < 4; ++i)
#pragma unroll
    for (int j = 0; j < 4; ++j) {
      size_t row = brow + tr + 16 * i, col = bcol + tc + 16 * j;
      out[row * OUT_F + col] = acc[i][j] + bb[col];
    }
}

extern "C" void kernel_launch(void* const* d_in, const int* in_sizes, int n_in,
                              void* d_out, int out_size, void* d_ws, size_t ws_size,
                              hipStream_t stream) {
  const float* x  = (const float*)d_in[0];
  const float* Wb = (const float*)d_in[1];
  const float* bb = (const float*)d_in[2];
  const float* A  = (const float*)d_in[3];
  const float* Bm = (const float*)d_in[4];
  const float* al = (const float*)d_in[5];
  const float* sc = (const float*)d_in[6];
  float* out = (float*)d_out;

  const size_t MB = (size_t)1 << 20;
  if (ws_size >= 96 * MB) {
    char* ws = (char*)d_ws;
    uint16_t* xh = (uint16_t*)(ws);             // 64 MB fp16
    uint16_t* wh = (uint16_t*)(ws + 64 * MB);   // 32 MB fp16
    conv_x_f16<<<(M_TOT * IN_F / 8) / 256, 256, 0, stream>>>(x, xh);
    merge_w_kernel<<<(OUT_F / 64) * (IN_F / 256), 256, 0, stream>>>(Wb, A, Bm, al, sc, wh);
    gemm_mrlora<<<(M_TOT / 256) * (OUT_F / 128), 256, 0, stream>>>(xh, wh, bb, out);
  } else {
    float* z = (float*)d_ws;  // needs 8192*63*4 ~= 2 MB
    fb_z_kernel<<<M_TOT, 256, 0, stream>>>(x, A, al, sc, z);
    fb_gemm_fp32<<<(M_TOT / 64) * (OUT_F / 64), 256, 0, stream>>>(x, Wb, bb, Bm, z, out);
  }
}